// Round 4
// baseline (302.977 us; speedup 1.0000x reference)
//
#include <hip/hip_runtime.h>

#define DIM   1024
#define DST   16
#define NSEQ  8192
#define NB    4

#define MT    64      // rows (n) per tile
#define KC2   64      // K-chunk per pipeline stage
#define NCH   16      // DIM / KC2
#define ATP   68      // padded at row stride (68 mod 32 = 4 -> 2-way = free)
#define NTILE 128     // NSEQ / MT

// ---------------------------------------------------------------------------
// Kernel A: T = x_tile @ A, 2-phase async pipeline (stage c+1 || compute c,
// one barrier per chunk). x staged HBM->LDS via global_load_lds (16B/lane);
// xs is lane-linear [64][64] with the swizzle applied on the GLOBAL source
// (quad q -> q ^ (seg&7), seg = row>>2) and matched on the LDS read, so
// 16-row reads spread across 8 bank-quads (2-way = free). Then the proven
// intra-tile scan epilogue (identical summation order to round-2 kernel).
// ---------------------------------------------------------------------------
__global__ __launch_bounds__(256) void kA_gemm_scan(
    const float* __restrict__ x, const float* __restrict__ A,
    float* __restrict__ Tloc, float* __restrict__ TS)
{
    __shared__ float xs[2][MT * KC2];      // 2 x 16,384 B (swizzled quads)
    __shared__ float at[2][DST * ATP];     // 2 x  4,352 B
    __shared__ float scanbuf[16 * DST];    //      1,024 B

    const int t    = threadIdx.x;
    const int b    = blockIdx.x >> 7;
    const int tile = blockIdx.x & 127;
    const int n0   = tile * MT;
    const int s    = t & 15;               // state index owned by this thread
    const int mg   = t >> 4;               // row-group 0..15 (4 rows each)
    const int w    = t >> 6;               // wave 0..3
    const int l    = t & 63;               // lane

    const float* xrow = x + ((long)(b * NSEQ + n0)) * DIM;

    float acc0 = 0.f, acc1 = 0.f, acc2 = 0.f, acc3 = 0.f;

    // ---- stage chunk c into buffer bb -------------------------------------
    auto stage = [&](int c, int bb) {
        const int kc = c * KC2;
        // x: 4 segments per wave; segment g covers rows 4g..4g+3 (1024 B).
        // Lane l -> row 4g + (l>>4), logical quad q = l&15, source pre-swizzled.
        #pragma unroll
        for (int i = 0; i < 4; ++i) {
            const int g   = w * 4 + i;
            const int row = 4 * g + (l >> 4);
            const int q   = l & 15;
            const float* src = xrow + (long)row * DIM + kc + 4 * (q ^ (g & 7));
            __builtin_amdgcn_global_load_lds(
                (const __attribute__((address_space(1))) void*)src,
                (__attribute__((address_space(3))) void*)&xs[bb][g * 256],
                16, 0, 0);
        }
        // A^T chunk: at[ss][kl] from A[kc+kl][ss] (coalesced reads, 2-way write)
        #pragma unroll
        for (int it = 0; it < 4; ++it) {
            const int idx = it * 256 + t;
            const int kl  = idx >> 4;      // 0..63
            const int ss  = idx & 15;
            at[bb][ss * ATP + kl] = A[(kc + kl) * DST + ss];
        }
    };

    // ---- compute chunk from buffer bb -------------------------------------
    auto compute = [&](int bb) {
        const float* xb = xs[bb];
        const float* ab = at[bb];
        #pragma unroll
        for (int kq = 0; kq < KC2 / 4; ++kq) {
            const float4 a  = *(const float4*)&ab[s * ATP + 4 * kq];
            const int   qp = 4 * (kq ^ (mg & 7));   // matches source swizzle
            const float4 x0 = *(const float4*)&xb[(mg * 4 + 0) * KC2 + qp];
            const float4 x1 = *(const float4*)&xb[(mg * 4 + 1) * KC2 + qp];
            const float4 x2 = *(const float4*)&xb[(mg * 4 + 2) * KC2 + qp];
            const float4 x3 = *(const float4*)&xb[(mg * 4 + 3) * KC2 + qp];
            acc0 += x0.x * a.x + x0.y * a.y + x0.z * a.z + x0.w * a.w;
            acc1 += x1.x * a.x + x1.y * a.y + x1.z * a.z + x1.w * a.w;
            acc2 += x2.x * a.x + x2.y * a.y + x2.z * a.z + x2.w * a.w;
            acc3 += x3.x * a.x + x3.y * a.y + x3.z * a.z + x3.w * a.w;
        }
    };

    stage(0, 0);
    __syncthreads();   // drains vmcnt(0): chunk 0 resident
    for (int c = 0; c < NCH; ++c) {
        const int cur = c & 1;
        if (c + 1 < NCH) stage(c + 1, cur ^ 1);   // loads in flight over compute
        compute(cur);
        __syncthreads();   // vmcnt+lgkm drain: next chunk ready, cur reusable
    }

    // ---- intra-tile inclusive scan over the 64 rows (proven epilogue) -----
    const float rsum = acc0 + acc1 + acc2 + acc3;
    scanbuf[mg * DST + s] = rsum;
    __syncthreads();
    float excl = 0.f, total = 0.f;
    #pragma unroll
    for (int m = 0; m < 16; ++m) {
        const float v = scanbuf[m * DST + s];   // 16 banks + broadcast: free
        total += v;
        excl  += (m < mg) ? v : 0.f;
    }
    if (mg == 0) TS[((long)b * NTILE + tile) * DST + s] = total;

    const float c0 = excl + acc0;
    const float c1 = c0 + acc1;
    const float c2 = c1 + acc2;
    const float c3 = c2 + acc3;
    *(float4*)&Tloc[((long)(b * DST + s)) * NSEQ + n0 + mg * 4] =
        make_float4(c0, c1, c2, c3);
}

// ---------------------------------------------------------------------------
// Kernel B: per-tile prefix base from TS (L2-hot), then out = (Tloc+base) @ D.
// Store-bound near floor; unchanged (proven in rounds 2-3).
// ---------------------------------------------------------------------------
__global__ __launch_bounds__(256) void kB_scan_out(
    const float* __restrict__ Tloc, const float* __restrict__ TS,
    const float* __restrict__ D, float* __restrict__ out)
{
    __shared__ float sp[MT * 20];
    __shared__ float partial[16 * DST];
    __shared__ float basebuf[DST];

    const int t    = threadIdx.x;
    const int b    = blockIdx.x >> 7;
    const int tile = blockIdx.x & 127;
    const int n0   = tile * MT;
    const int s    = t & 15;
    const int mg   = t >> 4;

    float4 dreg[16];
    #pragma unroll
    for (int ss = 0; ss < 16; ++ss)
        dreg[ss] = *(const float4*)&D[ss * DIM + 4 * t];

    {
        const float* tsb = TS + (long)b * NTILE * DST;
        float p = 0.f;
        for (int j = mg; j < tile; j += 16) p += tsb[j * DST + s];
        partial[mg * DST + s] = p;
    }
    __syncthreads();
    {
        float bsum = 0.f;
        #pragma unroll
        for (int m = 0; m < 16; ++m) bsum += partial[m * DST + s];
        if (mg == 0) basebuf[s] = bsum;
    }
    __syncthreads();

    #pragma unroll
    for (int j = 0; j < 4; ++j) {
        const int idx = j * 256 + t;
        const int ss  = idx >> 6;
        const int nn  = idx & 63;
        sp[nn * 20 + ss] = Tloc[((long)(b * DST + ss)) * NSEQ + n0 + nn] + basebuf[ss];
    }
    __syncthreads();

    float* ob = out + ((long)(b * NSEQ + n0)) * DIM + 4 * t;
    for (int r = 0; r < MT; ++r) {
        const float4 s0 = *(const float4*)&sp[r * 20 + 0];
        const float4 s1 = *(const float4*)&sp[r * 20 + 4];
        const float4 s2 = *(const float4*)&sp[r * 20 + 8];
        const float4 s3 = *(const float4*)&sp[r * 20 + 12];
        const float sv[16] = {s0.x, s0.y, s0.z, s0.w, s1.x, s1.y, s1.z, s1.w,
                              s2.x, s2.y, s2.z, s2.w, s3.x, s3.y, s3.z, s3.w};
        float4 o = make_float4(0.f, 0.f, 0.f, 0.f);
        #pragma unroll
        for (int ss = 0; ss < 16; ++ss) {
            o.x += sv[ss] * dreg[ss].x;
            o.y += sv[ss] * dreg[ss].y;
            o.z += sv[ss] * dreg[ss].z;
            o.w += sv[ss] * dreg[ss].w;
        }
        *(float4*)(ob + (long)r * DIM) = o;
    }
}

// ---------------------------------------------------------------------------
extern "C" void kernel_launch(void* const* d_in, const int* in_sizes, int n_in,
                              void* d_out, int out_size, void* d_ws, size_t ws_size,
                              hipStream_t stream) {
    const float* x = (const float*)d_in[0];   // [4, 8192, 1024]
    const float* A = (const float*)d_in[1];   // [1024, 16]
    const float* D = (const float*)d_in[2];   // [16, 1024]
    float* out  = (float*)d_out;              // [4, 8192, 1024]
    float* Tloc = (float*)d_ws;               // [4, 16, 8192] = 2 MiB
    float* TS   = Tloc + (long)NB * DST * NSEQ;  // [4, 128, 16] = 32 KiB

    kA_gemm_scan<<<dim3(NB * NTILE), dim3(256), 0, stream>>>(x, A, Tloc, TS);
    kB_scan_out <<<dim3(NB * NTILE), dim3(256), 0, stream>>>(Tloc, TS, D, out);
}

// Round 5
// 276.280 us; speedup vs baseline: 1.0966x; 1.0966x over previous
//
#include <hip/hip_runtime.h>

#define DIM   1024
#define DST   16
#define NSEQ  8192
#define NB    4

#define MT    64      // rows (n) per tile
#define KC2   64      // K-chunk per pipeline stage
#define NCH   16      // DIM / KC2
#define ATP   68      // padded at row stride (68 mod 32 = 4 -> conflict-free)
#define NTILE 128     // NSEQ / MT

// ---------------------------------------------------------------------------
// Kernel A: T = x_tile @ A. Reg-staged software pipeline, ONE barrier/chunk:
//   load x(c+1),A(c+1) -> regs ; compute(c) from LDS ; ds_write regs -> buf^1
// The vmcnt wait for the ds_writes lands AFTER compute (R4's bug was draining
// it before). Compute = R3's proven 4x4 K-split mapping: 8 ds_read_b128 per
// 64 FMAs, conflict-free (x: quad-XOR swizzle q^(mg&7), 2-way broadcast;
// at: 4 distinct rows stride-68). Epilogue = R3's reduce + intra-tile scan
// (identical summation order -> absmax unchanged).
// ---------------------------------------------------------------------------
__global__ __launch_bounds__(256) void kA_gemm_scan(
    const float* __restrict__ x, const float* __restrict__ A,
    float* __restrict__ Tloc, float* __restrict__ TS)
{
    __shared__ float xs[2][MT * KC2];      // 2 x 16 KB (swizzled quads)
    __shared__ float at[2][DST * ATP];     // 2 x 4.25 KB
    __shared__ float scanbuf[16 * DST];    // 1 KB

    const int t    = threadIdx.x;
    const int b    = blockIdx.x >> 7;
    const int tile = blockIdx.x & 127;
    const int n0   = tile * MT;

    const int w   = t >> 6;          // wave = k-quarter of each chunk
    const int mg  = (t >> 2) & 15;   // row group (4 rows each)
    const int sp  = t & 3;           // s = sp + 4j
    const int sq  = t & 15;          // staging: quad
    const int sm  = t >> 4;          // staging: base row (0..15)

    const float* xrow = x + ((long)(b * NSEQ + n0)) * DIM;

    float acc[4][4];
    #pragma unroll
    for (int r = 0; r < 4; ++r)
        #pragma unroll
        for (int j = 0; j < 4; ++j) acc[r][j] = 0.f;

    float4 xr0, xr1, xr2, xr3;       // staged x (4 rows x 16B)
    float  ar0, ar1, ar2, ar3;       // staged A^T elements

    // ---- issue global loads for chunk c into registers --------------------
#define LOADX(c) do { const int kc_ = (c) * KC2;                               \
    xr0 = *(const float4*)(xrow + (long)(sm +  0) * DIM + kc_ + 4 * sq);       \
    xr1 = *(const float4*)(xrow + (long)(sm + 16) * DIM + kc_ + 4 * sq);       \
    xr2 = *(const float4*)(xrow + (long)(sm + 32) * DIM + kc_ + 4 * sq);       \
    xr3 = *(const float4*)(xrow + (long)(sm + 48) * DIM + kc_ + 4 * sq);       \
    ar0 = A[(kc_ + ((0 * 256 + t) >> 4)) * DST + (t & 15)];                    \
    ar1 = A[(kc_ + ((1 * 256 + t) >> 4)) * DST + (t & 15)];                    \
    ar2 = A[(kc_ + ((2 * 256 + t) >> 4)) * DST + (t & 15)];                    \
    ar3 = A[(kc_ + ((3 * 256 + t) >> 4)) * DST + (t & 15)]; } while (0)

    // ---- write staged registers into LDS buffer bb ------------------------
#define STORE(bb) do {                                                         \
    *(float4*)&xs[bb][(sm +  0) * KC2 + 4 * (sq ^ (((sm +  0) >> 2) & 7))] = xr0; \
    *(float4*)&xs[bb][(sm + 16) * KC2 + 4 * (sq ^ (((sm + 16) >> 2) & 7))] = xr1; \
    *(float4*)&xs[bb][(sm + 32) * KC2 + 4 * (sq ^ (((sm + 32) >> 2) & 7))] = xr2; \
    *(float4*)&xs[bb][(sm + 48) * KC2 + 4 * (sq ^ (((sm + 48) >> 2) & 7))] = xr3; \
    at[bb][(t & 15) * ATP + ((0 * 256 + t) >> 4)] = ar0;                       \
    at[bb][(t & 15) * ATP + ((1 * 256 + t) >> 4)] = ar1;                       \
    at[bb][(t & 15) * ATP + ((2 * 256 + t) >> 4)] = ar2;                       \
    at[bb][(t & 15) * ATP + ((3 * 256 + t) >> 4)] = ar3; } while (0)

    // ---- compute chunk resident in buffer bb ------------------------------
#define COMPUTE(bb) do {                                                       \
    _Pragma("unroll")                                                          \
    for (int kq = 0; kq < 4; ++kq) {                                           \
        const int kb = w * 16 + 4 * kq;                                        \
        const float4 a0 = *(const float4*)&at[bb][(sp +  0) * ATP + kb];       \
        const float4 a1 = *(const float4*)&at[bb][(sp +  4) * ATP + kb];       \
        const float4 a2 = *(const float4*)&at[bb][(sp +  8) * ATP + kb];       \
        const float4 a3 = *(const float4*)&at[bb][(sp + 12) * ATP + kb];       \
        const int qs = 4 * ((w * 4 + kq) ^ (mg & 7));                          \
        _Pragma("unroll")                                                      \
        for (int r = 0; r < 4; ++r) {                                          \
            const float4 xv = *(const float4*)&xs[bb][(mg * 4 + r) * KC2 + qs];\
            acc[r][0] += xv.x * a0.x + xv.y * a0.y + xv.z * a0.z + xv.w * a0.w;\
            acc[r][1] += xv.x * a1.x + xv.y * a1.y + xv.z * a1.z + xv.w * a1.w;\
            acc[r][2] += xv.x * a2.x + xv.y * a2.y + xv.z * a2.z + xv.w * a2.w;\
            acc[r][3] += xv.x * a3.x + xv.y * a3.y + xv.z * a3.z + xv.w * a3.w;\
        }                                                                      \
    } } while (0)

    // prologue: chunk 0 resident
    LOADX(0);
    STORE(0);
    __syncthreads();

    for (int c = 0; c < NCH; ++c) {
        const int cur = c & 1;
        if (c + 1 < NCH) LOADX(c + 1);   // loads in flight across compute
        COMPUTE(cur);
        if (c + 1 < NCH) STORE(cur ^ 1); // vmcnt wait lands here, post-compute
        __syncthreads();
    }

    // ---- reduce 4 k-quarter partials via LDS (xs dead; alias it) ----------
    float* red = &xs[0][0];              // [4][64][17] = 4352 floats < 8192
    #pragma unroll
    for (int r = 0; r < 4; ++r)
        #pragma unroll
        for (int j = 0; j < 4; ++j)
            red[w * (64 * 17) + (mg * 4 + r) * 17 + (sp + 4 * j)] = acc[r][j];
    __syncthreads();

    const int s   = t & 15;              // final ownership: thread (s, mg2)
    const int mg2 = t >> 4;
    float acc0 = 0.f, acc1 = 0.f, acc2 = 0.f, acc3 = 0.f;
    #pragma unroll
    for (int q = 0; q < 4; ++q) {
        const float* rq = red + q * (64 * 17) + (mg2 * 4) * 17 + s;
        acc0 += rq[0 * 17];
        acc1 += rq[1 * 17];
        acc2 += rq[2 * 17];
        acc3 += rq[3 * 17];
    }
    __syncthreads();

    // ---- intra-tile inclusive scan over the 64 rows -----------------------
    const float rsum = acc0 + acc1 + acc2 + acc3;
    scanbuf[mg2 * DST + s] = rsum;
    __syncthreads();
    float excl = 0.f, total = 0.f;
    #pragma unroll
    for (int m = 0; m < 16; ++m) {
        const float v = scanbuf[m * DST + s];
        total += v;
        excl  += (m < mg2) ? v : 0.f;
    }
    if (mg2 == 0) TS[((long)b * NTILE + tile) * DST + s] = total;

    const float c0 = excl + acc0;
    const float c1 = c0 + acc1;
    const float c2 = c1 + acc2;
    const float c3 = c2 + acc3;
    *(float4*)&Tloc[((long)(b * DST + s)) * NSEQ + n0 + mg2 * 4] =
        make_float4(c0, c1, c2, c3);
#undef LOADX
#undef STORE
#undef COMPUTE
}

// ---------------------------------------------------------------------------
// Kernel B: per-tile prefix base from TS (L2-hot), then out = (Tloc+base) @ D.
// Store-bound near floor; unchanged (proven rounds 2-4).
// ---------------------------------------------------------------------------
__global__ __launch_bounds__(256) void kB_scan_out(
    const float* __restrict__ Tloc, const float* __restrict__ TS,
    const float* __restrict__ D, float* __restrict__ out)
{
    __shared__ float sp[MT * 20];
    __shared__ float partial[16 * DST];
    __shared__ float basebuf[DST];

    const int t    = threadIdx.x;
    const int b    = blockIdx.x >> 7;
    const int tile = blockIdx.x & 127;
    const int n0   = tile * MT;
    const int s    = t & 15;
    const int mg   = t >> 4;

    float4 dreg[16];
    #pragma unroll
    for (int ss = 0; ss < 16; ++ss)
        dreg[ss] = *(const float4*)&D[ss * DIM + 4 * t];

    {
        const float* tsb = TS + (long)b * NTILE * DST;
        float p = 0.f;
        for (int j = mg; j < tile; j += 16) p += tsb[j * DST + s];
        partial[mg * DST + s] = p;
    }
    __syncthreads();
    {
        float bsum = 0.f;
        #pragma unroll
        for (int m = 0; m < 16; ++m) bsum += partial[m * DST + s];
        if (mg == 0) basebuf[s] = bsum;
    }
    __syncthreads();

    #pragma unroll
    for (int j = 0; j < 4; ++j) {
        const int idx = j * 256 + t;
        const int ss  = idx >> 6;
        const int nn  = idx & 63;
        sp[nn * 20 + ss] = Tloc[((long)(b * DST + ss)) * NSEQ + n0 + nn] + basebuf[ss];
    }
    __syncthreads();

    float* ob = out + ((long)(b * NSEQ + n0)) * DIM + 4 * t;
    for (int r = 0; r < MT; ++r) {
        const float4 s0 = *(const float4*)&sp[r * 20 + 0];
        const float4 s1 = *(const float4*)&sp[r * 20 + 4];
        const float4 s2 = *(const float4*)&sp[r * 20 + 8];
        const float4 s3 = *(const float4*)&sp[r * 20 + 12];
        const float sv[16] = {s0.x, s0.y, s0.z, s0.w, s1.x, s1.y, s1.z, s1.w,
                              s2.x, s2.y, s2.z, s2.w, s3.x, s3.y, s3.z, s3.w};
        float4 o = make_float4(0.f, 0.f, 0.f, 0.f);
        #pragma unroll
        for (int ss = 0; ss < 16; ++ss) {
            o.x += sv[ss] * dreg[ss].x;
            o.y += sv[ss] * dreg[ss].y;
            o.z += sv[ss] * dreg[ss].z;
            o.w += sv[ss] * dreg[ss].w;
        }
        *(float4*)(ob + (long)r * DIM) = o;
    }
}

// ---------------------------------------------------------------------------
extern "C" void kernel_launch(void* const* d_in, const int* in_sizes, int n_in,
                              void* d_out, int out_size, void* d_ws, size_t ws_size,
                              hipStream_t stream) {
    const float* x = (const float*)d_in[0];   // [4, 8192, 1024]
    const float* A = (const float*)d_in[1];   // [1024, 16]
    const float* D = (const float*)d_in[2];   // [16, 1024]
    float* out  = (float*)d_out;              // [4, 8192, 1024]
    float* Tloc = (float*)d_ws;               // [4, 16, 8192] = 2 MiB
    float* TS   = Tloc + (long)NB * DST * NSEQ;  // [4, 128, 16] = 32 KiB

    kA_gemm_scan<<<dim3(NB * NTILE), dim3(256), 0, stream>>>(x, A, Tloc, TS);
    kB_scan_out <<<dim3(NB * NTILE), dim3(256), 0, stream>>>(Tloc, TS, D, out);
}

// Round 6
// 274.669 us; speedup vs baseline: 1.1031x; 1.0059x over previous
//
#include <hip/hip_runtime.h>

#define DIM   1024
#define DST   16
#define NSEQ  8192
#define NB    4

#define MT    64      // rows (n) per tile
#define NTILE 128     // NSEQ / MT
#define ATP   1032    // atb row pad (ushorts): breaks 2048B stride conflicts

typedef __attribute__((ext_vector_type(8))) short bf16x8;
typedef __attribute__((ext_vector_type(4))) float f32x4;

// fp32 -> bf16 round-to-nearest-even, pure bit ops (no header/API risk)
__device__ __forceinline__ unsigned short bfc(float f) {
    const unsigned u = __builtin_bit_cast(unsigned, f);
    return (unsigned short)((u + 0x7FFFu + ((u >> 16) & 1u)) >> 16);
}

__device__ __forceinline__ bf16x8 cvt8(float4 a, float4 b) {
    bf16x8 r;
    r[0] = (short)bfc(a.x); r[1] = (short)bfc(a.y);
    r[2] = (short)bfc(a.z); r[3] = (short)bfc(a.w);
    r[4] = (short)bfc(b.x); r[5] = (short)bfc(b.y);
    r[6] = (short)bfc(b.z); r[7] = (short)bfc(b.w);
    return r;
}

// ---------------------------------------------------------------------------
// Kernel A: T = x_tile @ A on the MATRIX cores (bf16 in, fp32 accum).
// Wave w owns rows w*16..w*16+15 x all 16 s over K=1024 = 32 chained
// mfma_f32_16x16x32_bf16. x-frag for lane l = 8 contiguous fp32 of row
// (l&15) at k=(l>>4)*8 -- loaded global->reg (2-chunk prefetch, no LDS, no
// barriers in the main loop). A is converted once to bf16 in LDS atb[s][k].
// Both frags use the same (lane,k) mapping, so any HW k-permutation cancels;
// C/D layout is the m89-verified col=lane&15, row=(lane>>4)*4+reg.
// Epilogue (reduce->scan->TS->Tloc) is the proven R2 code path.
// ---------------------------------------------------------------------------
__global__ __launch_bounds__(256) void kA_gemm_scan(
    const float* __restrict__ x, const float* __restrict__ A,
    float* __restrict__ Tloc, float* __restrict__ TS)
{
    __shared__ unsigned short atb[DST * ATP];  // 33,024 B  A^T in bf16
    __shared__ float red[MT * 20];             //  5,120 B  [row][s] tile
    __shared__ float scanbuf[16 * DST];        //  1,024 B

    const int t    = threadIdx.x;
    const int b    = blockIdx.x >> 7;
    const int tile = blockIdx.x & 127;
    const int n0   = tile * MT;
    const int w    = t >> 6;        // wave 0..3 -> rows w*16..
    const int l    = t & 63;
    const int lm   = l & 15;        // frag row (x) / frag col (A)
    const int lg   = l >> 4;        // k-group (8 elems each)

    // per-lane x pointer: row n0 + w*16 + lm, k base lg*8
    const float* xp = x + ((long)(b * NSEQ + n0 + w * 16 + lm)) * DIM + lg * 8;

    // prefetch chunks 0 and 1 (32 B per lane per chunk)
    float4 xa0 = *(const float4*)(xp + 0);
    float4 xa1 = *(const float4*)(xp + 4);
    float4 xb0 = *(const float4*)(xp + 32);
    float4 xb1 = *(const float4*)(xp + 36);

    // stage A as bf16: atb[s][k]  (A is [1024][16] row-major; idx = k*16+s)
    #pragma unroll
    for (int it = 0; it < 64; ++it) {
        const int idx = it * 256 + t;
        atb[(idx & 15) * ATP + (idx >> 4)] = bfc(A[idx]);
    }
    __syncthreads();

    const int aoff = lm * ATP + lg * 8;   // ushort index of this lane's B-frag

    f32x4 acc = {0.f, 0.f, 0.f, 0.f};
    #pragma unroll
    for (int c = 0; c < 32; ++c) {
        const bf16x8 af = cvt8(xa0, xa1);
        xa0 = xb0; xa1 = xb1;
        if (c + 2 < 32) {                  // rolling 2-deep prefetch
            xb0 = *(const float4*)(xp + 32 * (c + 2));
            xb1 = *(const float4*)(xp + 32 * (c + 2) + 4);
        }
        const bf16x8 bfr = *(const bf16x8*)&atb[aoff + 32 * c];
        acc = __builtin_amdgcn_mfma_f32_16x16x32_bf16(af, bfr, acc, 0, 0, 0);
    }

    // scatter D-frag to red[row][s]: row=(lane>>4)*4+reg, col(s)=lane&15
    #pragma unroll
    for (int r = 0; r < 4; ++r)
        red[(w * 16 + lg * 4 + r) * 20 + lm] = acc[r];
    __syncthreads();

    // ---- proven epilogue: thread (s, mg) owns 4 rows ----------------------
    const int s  = t & 15;
    const int mg = t >> 4;
    const float a0 = red[(mg * 4 + 0) * 20 + s];
    const float a1 = red[(mg * 4 + 1) * 20 + s];
    const float a2 = red[(mg * 4 + 2) * 20 + s];
    const float a3 = red[(mg * 4 + 3) * 20 + s];

    const float rsum = a0 + a1 + a2 + a3;
    scanbuf[mg * DST + s] = rsum;
    __syncthreads();
    float excl = 0.f, total = 0.f;
    #pragma unroll
    for (int m = 0; m < 16; ++m) {
        const float v = scanbuf[m * DST + s];   // 16 banks + broadcast: free
        total += v;
        excl  += (m < mg) ? v : 0.f;
    }
    if (mg == 0) TS[((long)b * NTILE + tile) * DST + s] = total;

    const float c0 = excl + a0;
    const float c1 = c0 + a1;
    const float c2 = c1 + a2;
    const float c3 = c2 + a3;
    *(float4*)&Tloc[((long)(b * DST + s)) * NSEQ + n0 + mg * 4] =
        make_float4(c0, c1, c2, c3);
}

// ---------------------------------------------------------------------------
// Kernel B: per-tile prefix base from TS (L2-hot), then out = (Tloc+base) @ D.
// Store-bound near floor; unchanged (proven rounds 2-5).
// ---------------------------------------------------------------------------
__global__ __launch_bounds__(256) void kB_scan_out(
    const float* __restrict__ Tloc, const float* __restrict__ TS,
    const float* __restrict__ D, float* __restrict__ out)
{
    __shared__ float sp[MT * 20];
    __shared__ float partial[16 * DST];
    __shared__ float basebuf[DST];

    const int t    = threadIdx.x;
    const int b    = blockIdx.x >> 7;
    const int tile = blockIdx.x & 127;
    const int n0   = tile * MT;
    const int s    = t & 15;
    const int mg   = t >> 4;

    float4 dreg[16];
    #pragma unroll
    for (int ss = 0; ss < 16; ++ss)
        dreg[ss] = *(const float4*)&D[ss * DIM + 4 * t];

    {
        const float* tsb = TS + (long)b * NTILE * DST;
        float p = 0.f;
        for (int j = mg; j < tile; j += 16) p += tsb[j * DST + s];
        partial[mg * DST + s] = p;
    }
    __syncthreads();
    {
        float bsum = 0.f;
        #pragma unroll
        for (int m = 0; m < 16; ++m) bsum += partial[m * DST + s];
        if (mg == 0) basebuf[s] = bsum;
    }
    __syncthreads();

    #pragma unroll
    for (int j = 0; j < 4; ++j) {
        const int idx = j * 256 + t;
        const int ss  = idx >> 6;
        const int nn  = idx & 63;
        sp[nn * 20 + ss] = Tloc[((long)(b * DST + ss)) * NSEQ + n0 + nn] + basebuf[ss];
    }
    __syncthreads();

    float* ob = out + ((long)(b * NSEQ + n0)) * DIM + 4 * t;
    for (int r = 0; r < MT; ++r) {
        const float4 s0 = *(const float4*)&sp[r * 20 + 0];
        const float4 s1 = *(const float4*)&sp[r * 20 + 4];
        const float4 s2 = *(const float4*)&sp[r * 20 + 8];
        const float4 s3 = *(const float4*)&sp[r * 20 + 12];
        const float sv[16] = {s0.x, s0.y, s0.z, s0.w, s1.x, s1.y, s1.z, s1.w,
                              s2.x, s2.y, s2.z, s2.w, s3.x, s3.y, s3.z, s3.w};
        float4 o = make_float4(0.f, 0.f, 0.f, 0.f);
        #pragma unroll
        for (int ss = 0; ss < 16; ++ss) {
            o.x += sv[ss] * dreg[ss].x;
            o.y += sv[ss] * dreg[ss].y;
            o.z += sv[ss] * dreg[ss].z;
            o.w += sv[ss] * dreg[ss].w;
        }
        *(float4*)(ob + (long)r * DIM) = o;
    }
}

// ---------------------------------------------------------------------------
extern "C" void kernel_launch(void* const* d_in, const int* in_sizes, int n_in,
                              void* d_out, int out_size, void* d_ws, size_t ws_size,
                              hipStream_t stream) {
    const float* x = (const float*)d_in[0];   // [4, 8192, 1024]
    const float* A = (const float*)d_in[1];   // [1024, 16]
    const float* D = (const float*)d_in[2];   // [16, 1024]
    float* out  = (float*)d_out;              // [4, 8192, 1024]
    float* Tloc = (float*)d_ws;               // [4, 16, 8192] = 2 MiB
    float* TS   = Tloc + (long)NB * DST * NSEQ;  // [4, 128, 16] = 32 KiB

    kA_gemm_scan<<<dim3(NB * NTILE), dim3(256), 0, stream>>>(x, A, Tloc, TS);
    kB_scan_out <<<dim3(NB * NTILE), dim3(256), 0, stream>>>(Tloc, TS, D, out);
}